// Round 1
// 616.197 us; speedup vs baseline: 1.1096x; 1.1096x over previous
//
#include <hip/hip_runtime.h>
#include <math.h>

#define B_ROWS 16384
#define DK     512
#define NK     4096
#define DV     512
#define H_MLP  32

typedef __attribute__((ext_vector_type(8))) short s16x8;
typedef __attribute__((ext_vector_type(4))) short s16x4;
typedef __attribute__((ext_vector_type(4))) float f32x4;

__device__ __forceinline__ short f2bf(float f) {
  unsigned u = __float_as_uint(f);
  u += 0x7fffu + ((u >> 16) & 1u);   // round-to-nearest-even
  return (short)(u >> 16);
}

__device__ __forceinline__ void async_cp16(const short* g, short* l) {
  __builtin_amdgcn_global_load_lds(
      (const __attribute__((address_space(1))) unsigned int*)g,
      (__attribute__((address_space(3))) unsigned int*)l, 16, 0, 0);
}

// ---------------------------------------------------------------------------
// fp32 -> bf16 convert (optional scale). n multiple of 2048.
// ---------------------------------------------------------------------------
__global__ __launch_bounds__(256) void cvt_bf16(const float* __restrict__ src,
                                                short* __restrict__ dst,
                                                long n, float scale) {
  long i = ((long)blockIdx.x * 256 + threadIdx.x) * 8;
  if (i >= n) return;
  float4 a = *(const float4*)(src + i);
  float4 b = *(const float4*)(src + i + 4);
  s16x8 o;
  o[0] = f2bf(a.x * scale); o[1] = f2bf(a.y * scale);
  o[2] = f2bf(a.z * scale); o[3] = f2bf(a.w * scale);
  o[4] = f2bf(b.x * scale); o[5] = f2bf(b.y * scale);
  o[6] = f2bf(b.z * scale); o[7] = f2bf(b.w * scale);
  *(s16x8*)(dst + i) = o;
}

// ---------------------------------------------------------------------------
// transpose values [NK x DV] fp32 -> vT [DV x NK] bf16
// ---------------------------------------------------------------------------
__global__ __launch_bounds__(256) void transpose_v(const float* __restrict__ v,
                                                   short* __restrict__ vT) {
  __shared__ float tile[32][33];
  const int tx = threadIdx.x & 31;
  const int ty = threadIdx.x >> 5;
  const int k0 = blockIdx.x * 32;   // over NK
  const int n0 = blockIdx.y * 32;   // over DV
#pragma unroll
  for (int j = 0; j < 4; ++j)
    tile[ty + j * 8][tx] = v[(long)(k0 + ty + j * 8) * DV + n0 + tx];
  __syncthreads();
#pragma unroll
  for (int j = 0; j < 4; ++j)
    vT[(long)(n0 + ty + j * 8) * NK + k0 + tx] = f2bf(tile[tx][ty + j * 8]);
}

// ---------------------------------------------------------------------------
// Staging: global -> LDS tile [128 rows][64 k] bf16, XOR-swizzled chunks.
// LDS slot (row, pos p in 0..7, 8 shorts/chunk) holds global chunk p^(row&7).
// ---------------------------------------------------------------------------
__device__ __forceinline__ void stage_f32_sw(const float* __restrict__ src, int ldk,
                                             int row0, int k0, short* lds, int tid) {
#pragma unroll
  for (int i = 0; i < 4; ++i) {
    int f   = i * 256 + tid;     // 0..1023
    int row = f >> 3;
    int p   = f & 7;
    int c   = p ^ (row & 7);
    const float* gp = src + (long)(row0 + row) * ldk + k0 + c * 8;
    float4 a = *(const float4*)gp;
    float4 b = *(const float4*)(gp + 4);
    s16x8 o;
    o[0] = f2bf(a.x); o[1] = f2bf(a.y); o[2] = f2bf(a.z); o[3] = f2bf(a.w);
    o[4] = f2bf(b.x); o[5] = f2bf(b.y); o[6] = f2bf(b.z); o[7] = f2bf(b.w);
    *(s16x8*)(lds + row * 64 + p * 8) = o;
  }
}

// async: wave w stages rows [w*32, w*32+32). Lane's LDS dest = base + lane*16B.
__device__ __forceinline__ void stage_bf_async(const short* __restrict__ src, int ldk,
                                               int row0, int k0, short* lds,
                                               int w, int lane) {
  const int srow = lane >> 3;              // 0..7
  const int c    = (lane & 7) ^ srow;      // swizzled source chunk
  const short* g = src + (long)(row0 + w * 32 + srow) * ldk + k0 + c * 8;
  short* lb = lds + w * 2048;              // wave-uniform
#pragma unroll
  for (int i = 0; i < 4; ++i)
    async_cp16(g + (long)(i * 8) * ldk, lb + i * 512);
}

// ---------------------------------------------------------------------------
// NT GEMM: C[M x N] = alpha * A[M x K] * B[N x K]^T, bf16 MFMA 16x16x32,
// 128x128 tile, BK=64. MODE 1 = bf16 source via global_load_lds, 0 = fp32+cvt.
// XCD-aware chunked block swizzle (grids here are always %8 == 0): blocks
// sharing an A-panel land on the same XCD's L2 (PV GEMM: 4 N-blocks/panel).
// ---------------------------------------------------------------------------
template <int AMODE, int BMODE>
__global__ __launch_bounds__(256) void gemm_nt(const void* __restrict__ Av,
                                               const void* __restrict__ Bv,
                                               float* __restrict__ C,
                                               int M, int N, int K, float alpha) {
  __shared__ short As[128 * 64];
  __shared__ short Bs[128 * 64];
  const int tid = threadIdx.x;

  const int nwg = gridDim.x * gridDim.y;
  const int bid = blockIdx.y * gridDim.x + blockIdx.x;
  const int per = nwg >> 3;                       // nwg % 8 == 0 always here
  const int swz = (bid & 7) * per + (bid >> 3);   // contiguous tiles per XCD
  const int bx  = swz % gridDim.x;
  const int by  = swz / gridDim.x;

  const int rowBase = by * 128;
  const int colBase = bx * 128;
  const int w = tid >> 6, lane = tid & 63;
  const int waveM = w >> 1, waveN = w & 1;
  const int quad = lane >> 4, lr = lane & 15;
  const int sw = lr & 7;

  f32x4 acc[4][4];
#pragma unroll
  for (int i = 0; i < 4; ++i)
#pragma unroll
    for (int j = 0; j < 4; ++j)
      acc[i][j] = (f32x4){0.f, 0.f, 0.f, 0.f};

  for (int k0 = 0; k0 < K; k0 += 64) {
    __syncthreads();
    if constexpr (AMODE)
      stage_bf_async((const short*)Av, K, rowBase, k0, As, w, lane);
    else
      stage_f32_sw((const float*)Av, K, rowBase, k0, As, tid);
    if constexpr (BMODE)
      stage_bf_async((const short*)Bv, K, colBase, k0, Bs, w, lane);
    else
      stage_f32_sw((const float*)Bv, K, colBase, k0, Bs, tid);
    __syncthreads();
#pragma unroll
    for (int ks = 0; ks < 2; ++ks) {
      const int cpos = ((ks * 4 + quad) ^ sw) * 8;
      s16x8 a[4], b[4];
#pragma unroll
      for (int t = 0; t < 4; ++t) {
        a[t] = *(const s16x8*)(As + (waveM * 64 + t * 16 + lr) * 64 + cpos);
        b[t] = *(const s16x8*)(Bs + (waveN * 64 + t * 16 + lr) * 64 + cpos);
      }
#pragma unroll
      for (int mt = 0; mt < 4; ++mt)
#pragma unroll
        for (int nt = 0; nt < 4; ++nt)
          acc[mt][nt] = __builtin_amdgcn_mfma_f32_16x16x32_bf16(a[mt], b[nt], acc[mt][nt], 0, 0, 0);
    }
  }

#pragma unroll
  for (int mt = 0; mt < 4; ++mt)
#pragma unroll
    for (int nt = 0; nt < 4; ++nt) {
      int col = colBase + waveN * 64 + nt * 16 + lr;
#pragma unroll
      for (int r = 0; r < 4; ++r) {
        int row = rowBase + waveM * 64 + mt * 16 + quad * 4 + r;
        C[(long)row * N + col] = acc[mt][nt][r] * alpha;
      }
    }
}

// ---------------------------------------------------------------------------
// Fused: per-row stats -> entropy -> MLP -> tau -> softmax write (fp32 + opt
// bf16 copy). One wave per row; the ENTIRE row lives in registers:
// 4096 f32 / 64 lanes = 16 float4/lane. Single global read, single write.
// Pass 2 overwrites v[] with exp((v-m)*itau) so the write pass is mul-only.
// ---------------------------------------------------------------------------
__global__ __launch_bounds__(256) void entropy_softmax(
    float* __restrict__ l, short* __restrict__ attn_bf,
    float* __restrict__ ent_out, float* __restrict__ tau_out,
    const float* __restrict__ w1, const float* __restrict__ b1,
    const float* __restrict__ w2, const float* __restrict__ b2) {
  const int wid = threadIdx.x >> 6, lane = threadIdx.x & 63;
  const int row = blockIdx.x * 4 + wid;
  float4* lr = (float4*)(l + (long)row * NK);

  // single global read: whole row into registers (16 dwordx4 in flight)
  float4 v[16];
#pragma unroll
  for (int it = 0; it < 16; ++it) v[it] = lr[it * 64 + lane];

  // pass 1 (registers): max, Z, E1 at base scale
  float m = -3.4e38f;
#pragma unroll
  for (int it = 0; it < 16; ++it)
    m = fmaxf(m, fmaxf(fmaxf(v[it].x, v[it].y), fmaxf(v[it].z, v[it].w)));
#pragma unroll
  for (int off = 32; off >= 1; off >>= 1) m = fmaxf(m, __shfl_xor(m, off));

  float Z = 0.f, E1 = 0.f;
#pragma unroll
  for (int it = 0; it < 16; ++it) {
    float e0 = __expf(v[it].x - m), e1 = __expf(v[it].y - m);
    float e2 = __expf(v[it].z - m), e3 = __expf(v[it].w - m);
    Z  += (e0 + e1) + (e2 + e3);
    E1 += v[it].x * e0 + v[it].y * e1 + v[it].z * e2 + v[it].w * e3;
  }
#pragma unroll
  for (int off = 32; off >= 1; off >>= 1) {
    Z  += __shfl_xor(Z, off);
    E1 += __shfl_xor(E1, off);
  }

  float entropy = m + __logf(Z) - E1 / Z;
  float en = fminf(fmaxf(entropy / 8.3177662f, 0.f), 1.f);  // / log(4096)

  float hp = 0.f;
  if (lane < H_MLP) {
    float x = en * w1[lane] + b1[lane];
    float g = 0.5f * x * (1.f + erff(x * 0.70710678f));     // exact GELU
    hp = g * w2[lane];
  }
#pragma unroll
  for (int off = 16; off >= 1; off >>= 1) hp += __shfl_xor(hp, off);
  hp = __shfl(hp, 0);

  float s    = 1.f / (1.f + __expf(-(hp + b2[0])));
  float tau  = 0.1f + 4.9f * s;
  float itau = 1.f / (tau + 1e-8f);
  if (lane == 0) { ent_out[row] = en; tau_out[row] = tau; }

  // pass 2 (registers): e2 = exp((v - m) * itau), overwrite v, accumulate Z2
  const float mi = m * itau;
  float Z2 = 0.f;
#pragma unroll
  for (int it = 0; it < 16; ++it) {
    v[it].x = __expf(fmaf(v[it].x, itau, -mi));
    v[it].y = __expf(fmaf(v[it].y, itau, -mi));
    v[it].z = __expf(fmaf(v[it].z, itau, -mi));
    v[it].w = __expf(fmaf(v[it].w, itau, -mi));
    Z2 += (v[it].x + v[it].y) + (v[it].z + v[it].w);
  }
#pragma unroll
  for (int off = 32; off >= 1; off >>= 1) Z2 += __shfl_xor(Z2, off);
  const float inv = 1.f / Z2;

  // pass 3 (registers): normalize + single write fp32 (+ bf16 copy)
  short* br = attn_bf ? attn_bf + (long)row * NK : nullptr;
#pragma unroll
  for (int it = 0; it < 16; ++it) {
    float4 p;
    p.x = v[it].x * inv; p.y = v[it].y * inv;
    p.z = v[it].z * inv; p.w = v[it].w * inv;
    lr[it * 64 + lane] = p;
    if (br) {
      s16x4 o;
      o.x = f2bf(p.x); o.y = f2bf(p.y); o.z = f2bf(p.z); o.w = f2bf(p.w);
      *(s16x4*)(br + (it * 64 + lane) * 4) = o;
    }
  }
}

// ---------------------------------------------------------------------------
extern "C" void kernel_launch(void* const* d_in, const int* in_sizes, int n_in,
                              void* d_out, int out_size, void* d_ws, size_t ws_size,
                              hipStream_t stream) {
  const float* q    = (const float*)d_in[0];
  const float* keys = (const float*)d_in[1];
  const float* vals = (const float*)d_in[2];
  const float* w1   = (const float*)d_in[3];
  const float* b1   = (const float*)d_in[4];
  const float* w2   = (const float*)d_in[5];
  const float* b2   = (const float*)d_in[6];

  float* out  = (float*)d_out;                 // [B, DV]
  float* attn = out + (long)B_ROWS * DV;       // [B, NK]  (l -> attn, in place)
  float* ent  = attn + (long)B_ROWS * NK;      // [B, 1]
  float* tau  = ent + B_ROWS;                  // [B, 1]

  char* ws = (char*)d_ws;
  const size_t off_vT    = 0;
  const size_t off_keysb = off_vT + (size_t)DV * NK * 2;
  const size_t off_qb    = off_keysb + (size_t)NK * DK * 2;
  const size_t off_attnb = off_qb + (size_t)B_ROWS * DK * 2;
  const size_t need_mid  = off_attnb;                              // ~24 MB
  const size_t need_full = off_attnb + (size_t)B_ROWS * NK * 2;    // ~158 MB

  short* vT    = (short*)(ws + off_vT);
  short* keysb = (short*)(ws + off_keysb);
  short* qb    = (short*)(ws + off_qb);
  short* attnb = (short*)(ws + off_attnb);

  const float base_scale = 0.044194173824159216f;  // 512^-0.5

  transpose_v<<<dim3(NK / 32, DV / 32), 256, 0, stream>>>(vals, vT);

  if (ws_size >= need_mid) {
    // bf16 operand prep (scale folded into q)
    cvt_bf16<<<(int)(((long)B_ROWS * DK) / 2048), 256, 0, stream>>>(
        q, qb, (long)B_ROWS * DK, base_scale);
    cvt_bf16<<<(int)(((long)NK * DK) / 2048), 256, 0, stream>>>(
        keys, keysb, (long)NK * DK, 1.0f);
    gemm_nt<1, 1><<<dim3(NK / 128, B_ROWS / 128), 256, 0, stream>>>(
        qb, keysb, attn, B_ROWS, NK, DK, 1.0f);
  } else {
    gemm_nt<0, 0><<<dim3(NK / 128, B_ROWS / 128), 256, 0, stream>>>(
        q, keys, attn, B_ROWS, NK, DK, base_scale);
  }

  const bool full = ws_size >= need_full;
  entropy_softmax<<<B_ROWS / 4, 256, 0, stream>>>(
      attn, full ? attnb : nullptr, ent, tau, w1, b1, w2, b2);

  if (full)
    gemm_nt<1, 1><<<dim3(DV / 128, B_ROWS / 128), 256, 0, stream>>>(
        attnb, vT, out, B_ROWS, DV, NK, 1.0f);
  else
    gemm_nt<0, 1><<<dim3(DV / 128, B_ROWS / 128), 256, 0, stream>>>(
        attn, vT, out, B_ROWS, DV, NK, 1.0f);
}

// Round 2
// 609.316 us; speedup vs baseline: 1.1221x; 1.0113x over previous
//
#include <hip/hip_runtime.h>
#include <math.h>

#define B_ROWS 16384
#define DK     512
#define NK     4096
#define DV     512
#define H_MLP  32

typedef __attribute__((ext_vector_type(8))) short s16x8;
typedef __attribute__((ext_vector_type(4))) short s16x4;
typedef __attribute__((ext_vector_type(4))) float f32x4;

__device__ __forceinline__ short f2bf(float f) {
  unsigned u = __float_as_uint(f);
  u += 0x7fffu + ((u >> 16) & 1u);   // round-to-nearest-even
  return (short)(u >> 16);
}

__device__ __forceinline__ void async_cp16(const short* g, short* l) {
  __builtin_amdgcn_global_load_lds(
      (const __attribute__((address_space(1))) unsigned int*)g,
      (__attribute__((address_space(3))) unsigned int*)l, 16, 0, 0);
}

// ---------------------------------------------------------------------------
// fp32 -> bf16 convert (optional scale). n multiple of 2048.
// ---------------------------------------------------------------------------
__global__ __launch_bounds__(256) void cvt_bf16(const float* __restrict__ src,
                                                short* __restrict__ dst,
                                                long n, float scale) {
  long i = ((long)blockIdx.x * 256 + threadIdx.x) * 8;
  if (i >= n) return;
  float4 a = *(const float4*)(src + i);
  float4 b = *(const float4*)(src + i + 4);
  s16x8 o;
  o[0] = f2bf(a.x * scale); o[1] = f2bf(a.y * scale);
  o[2] = f2bf(a.z * scale); o[3] = f2bf(a.w * scale);
  o[4] = f2bf(b.x * scale); o[5] = f2bf(b.y * scale);
  o[6] = f2bf(b.z * scale); o[7] = f2bf(b.w * scale);
  *(s16x8*)(dst + i) = o;
}

// ---------------------------------------------------------------------------
// transpose values [NK x DV] fp32 -> vT [DV x NK] bf16
// ---------------------------------------------------------------------------
__global__ __launch_bounds__(256) void transpose_v(const float* __restrict__ v,
                                                   short* __restrict__ vT) {
  __shared__ float tile[32][33];
  const int tx = threadIdx.x & 31;
  const int ty = threadIdx.x >> 5;
  const int k0 = blockIdx.x * 32;   // over NK
  const int n0 = blockIdx.y * 32;   // over DV
#pragma unroll
  for (int j = 0; j < 4; ++j)
    tile[ty + j * 8][tx] = v[(long)(k0 + ty + j * 8) * DV + n0 + tx];
  __syncthreads();
#pragma unroll
  for (int j = 0; j < 4; ++j)
    vT[(long)(n0 + ty + j * 8) * NK + k0 + tx] = f2bf(tile[tx][ty + j * 8]);
}

// ---------------------------------------------------------------------------
// Staging: global -> LDS tile [rows][64 k] bf16, XOR-swizzled chunks.
// LDS slot (row, pos p in 0..7, 8 shorts/chunk) holds global chunk p^(row&7).
// ---------------------------------------------------------------------------
__device__ __forceinline__ void stage_f32_sw(const float* __restrict__ src, int ldk,
                                             int row0, int k0, short* lds, int tid) {
#pragma unroll
  for (int i = 0; i < 4; ++i) {
    int f   = i * 256 + tid;     // 0..1023
    int row = f >> 3;
    int p   = f & 7;
    int c   = p ^ (row & 7);
    const float* gp = src + (long)(row0 + row) * ldk + k0 + c * 8;
    float4 a = *(const float4*)gp;
    float4 b = *(const float4*)(gp + 4);
    s16x8 o;
    o[0] = f2bf(a.x); o[1] = f2bf(a.y); o[2] = f2bf(a.z); o[3] = f2bf(a.w);
    o[4] = f2bf(b.x); o[5] = f2bf(b.y); o[6] = f2bf(b.z); o[7] = f2bf(b.w);
    *(s16x8*)(lds + row * 64 + p * 8) = o;
  }
}

// async: wave w stages rows [w*RPW, (w+1)*RPW). Lane's LDS dest = base+lane*16B.
// Source chunk pre-swizzled so LDS slot (row,p) holds global chunk p^(row&7).
template <int RPW>
__device__ __forceinline__ void stage_bf_async(const short* __restrict__ src, int ldk,
                                               int row0, int k0, short* lds,
                                               int w, int lane) {
  const int srow = lane >> 3;              // 0..7
  const int c    = (lane & 7) ^ srow;      // swizzled source chunk
  const short* g = src + (long)(row0 + w * RPW + srow) * ldk + k0 + c * 8;
  short* lb = lds + w * RPW * 64;          // wave-uniform
#pragma unroll
  for (int i = 0; i < RPW / 8; ++i)
    async_cp16(g + (long)(i * 8) * ldk, lb + i * 512);
}

// ---------------------------------------------------------------------------
// Legacy NT GEMM (fallback paths with fp32 sources): 128x128 tile, 2-barrier.
// ---------------------------------------------------------------------------
template <int AMODE, int BMODE>
__global__ __launch_bounds__(256) void gemm_nt(const void* __restrict__ Av,
                                               const void* __restrict__ Bv,
                                               float* __restrict__ C,
                                               int M, int N, int K, float alpha) {
  __shared__ short As[128 * 64];
  __shared__ short Bs[128 * 64];
  const int tid = threadIdx.x;

  const int nwg = gridDim.x * gridDim.y;
  const int bid = blockIdx.y * gridDim.x + blockIdx.x;
  const int per = nwg >> 3;
  const int swz = (bid & 7) * per + (bid >> 3);
  const int bx  = swz % gridDim.x;
  const int by  = swz / gridDim.x;

  const int rowBase = by * 128;
  const int colBase = bx * 128;
  const int w = tid >> 6, lane = tid & 63;
  const int waveM = w >> 1, waveN = w & 1;
  const int quad = lane >> 4, lr = lane & 15;
  const int sw = lr & 7;

  f32x4 acc[4][4];
#pragma unroll
  for (int i = 0; i < 4; ++i)
#pragma unroll
    for (int j = 0; j < 4; ++j)
      acc[i][j] = (f32x4){0.f, 0.f, 0.f, 0.f};

  for (int k0 = 0; k0 < K; k0 += 64) {
    __syncthreads();
    if constexpr (AMODE)
      stage_bf_async<32>((const short*)Av, K, rowBase, k0, As, w, lane);
    else
      stage_f32_sw((const float*)Av, K, rowBase, k0, As, tid);
    if constexpr (BMODE)
      stage_bf_async<32>((const short*)Bv, K, colBase, k0, Bs, w, lane);
    else
      stage_f32_sw((const float*)Bv, K, colBase, k0, Bs, tid);
    __syncthreads();
#pragma unroll
    for (int ks = 0; ks < 2; ++ks) {
      const int cpos = ((ks * 4 + quad) ^ sw) * 8;
      s16x8 a[4], b[4];
#pragma unroll
      for (int t = 0; t < 4; ++t) {
        a[t] = *(const s16x8*)(As + (waveM * 64 + t * 16 + lr) * 64 + cpos);
        b[t] = *(const s16x8*)(Bs + (waveN * 64 + t * 16 + lr) * 64 + cpos);
      }
#pragma unroll
      for (int mt = 0; mt < 4; ++mt)
#pragma unroll
        for (int nt = 0; nt < 4; ++nt)
          acc[mt][nt] = __builtin_amdgcn_mfma_f32_16x16x32_bf16(a[mt], b[nt], acc[mt][nt], 0, 0, 0);
    }
  }

#pragma unroll
  for (int mt = 0; mt < 4; ++mt)
#pragma unroll
    for (int nt = 0; nt < 4; ++nt) {
      int col = colBase + waveN * 64 + nt * 16 + lr;
#pragma unroll
      for (int r = 0; r < 4; ++r) {
        int row = rowBase + waveM * 64 + mt * 16 + quad * 4 + r;
        C[(long)row * N + col] = acc[mt][nt][r] * alpha;
      }
    }
}

// ---------------------------------------------------------------------------
// 2-phase pipelined NT GEMM (T3-minimum + T5, catalog §5.5), bf16 sources only.
// Per K-tile (BK=64): issue next-tile global_load_lds FIRST, compute current
// buffer, then ONE vmcnt(0)+s_barrier. The stage latency hides under the MFMA
// cluster instead of being drained cold at a __syncthreads.
// Race-safety: stage at iter t targets buf[cur^1], last read during iter t-1,
// and every wave passed the end-of-(t-1) barrier before issuing. vmcnt(0) +
// barrier at iter end guarantee all waves' loads landed before buf is read.
// sched_barrier(0) fences code motion across the raw barriers (rule #18).
// ---------------------------------------------------------------------------
template <int BM, int BN, int WM, int WN>
__global__ __launch_bounds__(WM * WN * 64, 2) void gemm_nt_2ph(
    const short* __restrict__ A, const short* __restrict__ B,
    float* __restrict__ C, int M, int N, int K, float alpha) {
  constexpr int NWAVE = WM * WN;
  constexpr int MR = BM / WM / 16;
  constexpr int NR = BN / WN / 16;
  __shared__ short As[2 * BM * 64];
  __shared__ short Bs[2 * BN * 64];

  const int tid = threadIdx.x;
  const int nwg = gridDim.x * gridDim.y;
  const int bid = blockIdx.y * gridDim.x + blockIdx.x;
  const int per = nwg >> 3;                       // nwg % 8 == 0 always here
  const int swz = (bid & 7) * per + (bid >> 3);   // contiguous tiles per XCD
  const int bx  = swz % gridDim.x;
  const int by  = swz / gridDim.x;

  const int rowBase = by * BM;
  const int colBase = bx * BN;
  const int w = tid >> 6, lane = tid & 63;
  const int waveM = w / WN, waveN = w % WN;
  const int quad = lane >> 4, lr = lane & 15, sw = lr & 7;

  f32x4 acc[MR][NR];
#pragma unroll
  for (int i = 0; i < MR; ++i)
#pragma unroll
    for (int j = 0; j < NR; ++j)
      acc[i][j] = (f32x4){0.f, 0.f, 0.f, 0.f};

  auto compute = [&](const short* Ab, const short* Bb) {
#pragma unroll
    for (int ks = 0; ks < 2; ++ks) {
      const int cpos = ((ks * 4 + quad) ^ sw) * 8;
      s16x8 a[MR], b[NR];
#pragma unroll
      for (int mt = 0; mt < MR; ++mt)
        a[mt] = *(const s16x8*)(Ab + (waveM * (BM / WM) + mt * 16 + lr) * 64 + cpos);
#pragma unroll
      for (int nt = 0; nt < NR; ++nt)
        b[nt] = *(const s16x8*)(Bb + (waveN * (BN / WN) + nt * 16 + lr) * 64 + cpos);
      __builtin_amdgcn_s_setprio(1);
#pragma unroll
      for (int mt = 0; mt < MR; ++mt)
#pragma unroll
        for (int nt = 0; nt < NR; ++nt)
          acc[mt][nt] = __builtin_amdgcn_mfma_f32_16x16x32_bf16(a[mt], b[nt], acc[mt][nt], 0, 0, 0);
      __builtin_amdgcn_s_setprio(0);
    }
  };

  const int NT = K >> 6;

  // prologue: stage tile 0 into buf0, full drain once.
  stage_bf_async<BM / NWAVE>(A, K, rowBase, 0, As, w, lane);
  stage_bf_async<BN / NWAVE>(B, K, colBase, 0, Bs, w, lane);
  asm volatile("s_waitcnt vmcnt(0)" ::: "memory");
  __builtin_amdgcn_s_barrier();
  __builtin_amdgcn_sched_barrier(0);

  int cur = 0;
  for (int t = 0; t < NT - 1; ++t) {
    const int nxt = cur ^ 1;
    // issue next-tile loads FIRST (latency hides under this tile's MFMA)
    stage_bf_async<BM / NWAVE>(A, K, rowBase, (t + 1) * 64, As + nxt * BM * 64, w, lane);
    stage_bf_async<BN / NWAVE>(B, K, colBase, (t + 1) * 64, Bs + nxt * BN * 64, w, lane);
    __builtin_amdgcn_sched_barrier(0);
    compute(As + cur * BM * 64, Bs + cur * BN * 64);
    asm volatile("s_waitcnt vmcnt(0)" ::: "memory");
    __builtin_amdgcn_s_barrier();
    __builtin_amdgcn_sched_barrier(0);
    cur = nxt;
  }
  compute(As + cur * BM * 64, Bs + cur * BN * 64);

#pragma unroll
  for (int mt = 0; mt < MR; ++mt)
#pragma unroll
    for (int nt = 0; nt < NR; ++nt) {
      int col = colBase + waveN * (BN / WN) + nt * 16 + lr;
#pragma unroll
      for (int r = 0; r < 4; ++r) {
        int row = rowBase + waveM * (BM / WM) + mt * 16 + quad * 4 + r;
        C[(long)row * N + col] = acc[mt][nt][r] * alpha;
      }
    }
}

// ---------------------------------------------------------------------------
// Fused: per-row stats -> entropy -> MLP -> tau -> softmax write (fp32 + opt
// bf16 copy). One wave per row; the ENTIRE row lives in registers:
// 4096 f32 / 64 lanes = 16 float4/lane. Single global read, single write.
// ---------------------------------------------------------------------------
__global__ __launch_bounds__(256) void entropy_softmax(
    float* __restrict__ l, short* __restrict__ attn_bf,
    float* __restrict__ ent_out, float* __restrict__ tau_out,
    const float* __restrict__ w1, const float* __restrict__ b1,
    const float* __restrict__ w2, const float* __restrict__ b2) {
  const int wid = threadIdx.x >> 6, lane = threadIdx.x & 63;
  const int row = blockIdx.x * 4 + wid;
  float4* lr = (float4*)(l + (long)row * NK);

  // single global read: whole row into registers (16 dwordx4 in flight)
  float4 v[16];
#pragma unroll
  for (int it = 0; it < 16; ++it) v[it] = lr[it * 64 + lane];

  // pass 1 (registers): max, Z, E1 at base scale
  float m = -3.4e38f;
#pragma unroll
  for (int it = 0; it < 16; ++it)
    m = fmaxf(m, fmaxf(fmaxf(v[it].x, v[it].y), fmaxf(v[it].z, v[it].w)));
#pragma unroll
  for (int off = 32; off >= 1; off >>= 1) m = fmaxf(m, __shfl_xor(m, off));

  float Z = 0.f, E1 = 0.f;
#pragma unroll
  for (int it = 0; it < 16; ++it) {
    float e0 = __expf(v[it].x - m), e1 = __expf(v[it].y - m);
    float e2 = __expf(v[it].z - m), e3 = __expf(v[it].w - m);
    Z  += (e0 + e1) + (e2 + e3);
    E1 += v[it].x * e0 + v[it].y * e1 + v[it].z * e2 + v[it].w * e3;
  }
#pragma unroll
  for (int off = 32; off >= 1; off >>= 1) {
    Z  += __shfl_xor(Z, off);
    E1 += __shfl_xor(E1, off);
  }

  float entropy = m + __logf(Z) - E1 / Z;
  float en = fminf(fmaxf(entropy / 8.3177662f, 0.f), 1.f);  // / log(4096)

  float hp = 0.f;
  if (lane < H_MLP) {
    float x = en * w1[lane] + b1[lane];
    float g = 0.5f * x * (1.f + erff(x * 0.70710678f));     // exact GELU
    hp = g * w2[lane];
  }
#pragma unroll
  for (int off = 16; off >= 1; off >>= 1) hp += __shfl_xor(hp, off);
  hp = __shfl(hp, 0);

  float s    = 1.f / (1.f + __expf(-(hp + b2[0])));
  float tau  = 0.1f + 4.9f * s;
  float itau = 1.f / (tau + 1e-8f);
  if (lane == 0) { ent_out[row] = en; tau_out[row] = tau; }

  // pass 2 (registers): e2 = exp((v - m) * itau), overwrite v, accumulate Z2
  const float mi = m * itau;
  float Z2 = 0.f;
#pragma unroll
  for (int it = 0; it < 16; ++it) {
    v[it].x = __expf(fmaf(v[it].x, itau, -mi));
    v[it].y = __expf(fmaf(v[it].y, itau, -mi));
    v[it].z = __expf(fmaf(v[it].z, itau, -mi));
    v[it].w = __expf(fmaf(v[it].w, itau, -mi));
    Z2 += (v[it].x + v[it].y) + (v[it].z + v[it].w);
  }
#pragma unroll
  for (int off = 32; off >= 1; off >>= 1) Z2 += __shfl_xor(Z2, off);
  const float inv = 1.f / Z2;

  // pass 3 (registers): normalize + single write fp32 (+ bf16 copy)
  short* br = attn_bf ? attn_bf + (long)row * NK : nullptr;
#pragma unroll
  for (int it = 0; it < 16; ++it) {
    float4 p;
    p.x = v[it].x * inv; p.y = v[it].y * inv;
    p.z = v[it].z * inv; p.w = v[it].w * inv;
    lr[it * 64 + lane] = p;
    if (br) {
      s16x4 o;
      o.x = f2bf(p.x); o.y = f2bf(p.y); o.z = f2bf(p.z); o.w = f2bf(p.w);
      *(s16x4*)(br + (it * 64 + lane) * 4) = o;
    }
  }
}

// ---------------------------------------------------------------------------
extern "C" void kernel_launch(void* const* d_in, const int* in_sizes, int n_in,
                              void* d_out, int out_size, void* d_ws, size_t ws_size,
                              hipStream_t stream) {
  const float* q    = (const float*)d_in[0];
  const float* keys = (const float*)d_in[1];
  const float* vals = (const float*)d_in[2];
  const float* w1   = (const float*)d_in[3];
  const float* b1   = (const float*)d_in[4];
  const float* w2   = (const float*)d_in[5];
  const float* b2   = (const float*)d_in[6];

  float* out  = (float*)d_out;                 // [B, DV]
  float* attn = out + (long)B_ROWS * DV;       // [B, NK]  (l -> attn, in place)
  float* ent  = attn + (long)B_ROWS * NK;      // [B, 1]
  float* tau  = ent + B_ROWS;                  // [B, 1]

  char* ws = (char*)d_ws;
  const size_t off_vT    = 0;
  const size_t off_keysb = off_vT + (size_t)DV * NK * 2;
  const size_t off_qb    = off_keysb + (size_t)NK * DK * 2;
  const size_t off_attnb = off_qb + (size_t)B_ROWS * DK * 2;
  const size_t need_mid  = off_attnb;                              // ~24 MB
  const size_t need_full = off_attnb + (size_t)B_ROWS * NK * 2;    // ~158 MB

  short* vT    = (short*)(ws + off_vT);
  short* keysb = (short*)(ws + off_keysb);
  short* qb    = (short*)(ws + off_qb);
  short* attnb = (short*)(ws + off_attnb);

  const float base_scale = 0.044194173824159216f;  // 512^-0.5

  transpose_v<<<dim3(NK / 32, DV / 32), 256, 0, stream>>>(vals, vT);

  if (ws_size >= need_mid) {
    // bf16 operand prep (scale folded into q)
    cvt_bf16<<<(int)(((long)B_ROWS * DK) / 2048), 256, 0, stream>>>(
        q, qb, (long)B_ROWS * DK, base_scale);
    cvt_bf16<<<(int)(((long)NK * DK) / 2048), 256, 0, stream>>>(
        keys, keysb, (long)NK * DK, 1.0f);
    // 2-phase 256x256 tile, 8 waves: grid 16x64 = 1024 wg (chip stays full)
    gemm_nt_2ph<256, 256, 2, 4><<<dim3(NK / 256, B_ROWS / 256), 512, 0, stream>>>(
        qb, keysb, attn, B_ROWS, NK, DK, 1.0f);
  } else {
    gemm_nt<0, 0><<<dim3(NK / 128, B_ROWS / 128), 256, 0, stream>>>(
        q, keys, attn, B_ROWS, NK, DK, base_scale);
  }

  const bool full = ws_size >= need_full;
  entropy_softmax<<<B_ROWS / 4, 256, 0, stream>>>(
      attn, full ? attnb : nullptr, ent, tau, w1, b1, w2, b2);

  if (full)
    // 2-phase 128x128 tile, 4 waves: N=512 keeps grid at 512 wg (2 blocks/CU)
    gemm_nt_2ph<128, 128, 2, 2><<<dim3(DV / 128, B_ROWS / 128), 256, 0, stream>>>(
        attnb, vT, out, B_ROWS, DV, NK, 1.0f);
  else
    gemm_nt<0, 1><<<dim3(DV / 128, B_ROWS / 128), 256, 0, stream>>>(
        attn, vT, out, B_ROWS, DV, NK, 1.0f);
}